// Round 13
// baseline (213.553 us; speedup 1.0000x reference)
//
#include <hip/hip_runtime.h>
#include <hip/hip_bf16.h>
#include <stdint.h>
#include <math.h>

#define NROWS 16384
#define DHALF 384
#define DFULL 768
#define ROWB  384      // bytes per fp4 row: 768 elems * 4 bit
#define EPSF  1e-8f
#define QSCALE 64.0f   // N(0,0.036)*64 -> N(0,2.3): centered in e2m1 range +-6

typedef __attribute__((ext_vector_type(4)))  float f32x4;
typedef __attribute__((ext_vector_type(4)))  int   int4v;
typedef __attribute__((ext_vector_type(8)))  int   int8v;

// ---- async global->LDS, 16B per lane (wave-uniform base + lane*16) ----
__device__ __forceinline__ void async_copy16(const void* gptr, void* lptr) {
    __builtin_amdgcn_global_load_lds(
        (const __attribute__((address_space(1))) unsigned int*)gptr,
        (__attribute__((address_space(3))) unsigned int*)lptr,
        16, 0, 0);
}

// monotone float->u32 (order-preserving for all finite floats)
__device__ __forceinline__ unsigned mono_u32(float v) {
    unsigned u = __float_as_uint(v);
    return u ^ ((unsigned)(((int)u) >> 31) | 0x80000000u);
}

// max with a DPP row_ror'd copy (16-lane row, pure VALU — no LDS traffic)
template <int CTRL>
__device__ __forceinline__ unsigned row_max_step(unsigned v) {
    unsigned t = (unsigned)__builtin_amdgcn_update_dpp(
        0, (int)v, CTRL, 0xF, 0xF, false);
    return v > t ? v : t;
}

// fp4 e2m1 encode, round-to-nearest: values {0,.5,1,1.5,2,3,4,6} (+sign)
__device__ __forceinline__ unsigned enc_fp4(float v) {
    float a = fabsf(v);
    unsigned c = (unsigned)(a >= 0.25f) + (a >= 0.75f) + (a >= 1.25f) +
                 (a >= 1.75f) + (a >= 2.5f) + (a >= 3.5f) + (a >= 5.0f);
    return c | (v < 0.0f ? 8u : 0u);
}

// fp32 -> bf16 bits, round-to-nearest-even (no NaN inputs here)
__device__ __forceinline__ unsigned f2bf(float f) {
    unsigned u = __float_as_uint(f);
    return (u + (((u >> 16) & 1u) + 0x7fffu)) >> 16;
}
__device__ __forceinline__ float bf_lo(unsigned w) { return __uint_as_float(w << 16); }
__device__ __forceinline__ float bf_hi(unsigned w) { return __uint_as_float(w & 0xffff0000u); }

// fp4 operand: HW reads only v[0:3] of the 8-reg tuple (cbsz/blgp=4);
// high half compile-time zero (R10).
__device__ __forceinline__ int8v to8(int4v q) {
    int8v r;
    r[0] = q[0]; r[1] = q[1]; r[2] = q[2]; r[3] = q[3];
    r[4] = 0; r[5] = 0; r[6] = 0; r[7] = 0;
    return r;
}

// ---------------------------------------------------------------------
// Kernel 1: per-row L2 norm over concat(a,b); write fp4-e2m1 nibbles of
// (x_norm * 64). Optionally bf16 normalized rows (xb) for loss gather.
// Zeroes best[row] and out[0] (loss accumulates atomically later).
// ---------------------------------------------------------------------
__global__ __launch_bounds__(256) void normalize_kernel(
    const float* __restrict__ a, const float* __restrict__ b,
    unsigned char* __restrict__ xq, float* __restrict__ invn,
    unsigned long long* __restrict__ best,
    unsigned* __restrict__ xb,             // nullable
    float* __restrict__ out) {
    int wave = threadIdx.x >> 6;
    int lane = threadIdx.x & 63;
    int row  = blockIdx.x * 4 + wave;
    if (threadIdx.x == 0 && blockIdx.x == 0) out[0] = 0.0f;

    const float2* pa = (const float2*)(a + (size_t)row * DHALF);  // 192 pairs
    const float2* pb = (const float2*)(b + (size_t)row * DHALF);

    float2 va[3], vb[3];
    float s = 0.0f;
#pragma unroll
    for (int it = 0; it < 3; ++it) {
        va[it] = pa[lane + 64 * it];
        s += va[it].x * va[it].x + va[it].y * va[it].y;
    }
#pragma unroll
    for (int it = 0; it < 3; ++it) {
        vb[it] = pb[lane + 64 * it];
        s += vb[it].x * vb[it].x + vb[it].y * vb[it].y;
    }
#pragma unroll
    for (int d = 1; d < 64; d <<= 1) s += __shfl_xor(s, d, 64);

    float inv = 1.0f / fmaxf(sqrtf(s), EPSF);
    if (lane == 0) { invn[row] = inv; best[row] = 0ull; }
    float qs = inv * QSCALE;

    unsigned char* px = xq + (size_t)row * ROWB;
#pragma unroll
    for (int it = 0; it < 3; ++it)
        px[lane + 64 * it] =
            (unsigned char)(enc_fp4(va[it].x * qs) | (enc_fp4(va[it].y * qs) << 4));
#pragma unroll
    for (int it = 0; it < 3; ++it)
        px[192 + lane + 64 * it] =
            (unsigned char)(enc_fp4(vb[it].x * qs) | (enc_fp4(vb[it].y * qs) << 4));

    if (xb) {   // uniform branch
        unsigned* pw = xb + (size_t)row * (DFULL / 2);   // 384 packed pairs
#pragma unroll
        for (int it = 0; it < 3; ++it)
            pw[lane + 64 * it] =
                f2bf(va[it].x * inv) | (f2bf(va[it].y * inv) << 16);
#pragma unroll
        for (int it = 0; it < 3; ++it)
            pw[192 + lane + 64 * it] =
                f2bf(vb[it].x * inv) | (f2bf(vb[it].y * inv) << 16);
    }
}

// ---------------------------------------------------------------------
// Kernel 2: scaled dots via MX-fp4 16x16x128 MFMA, 128x128 tile, BK=128
// elems = 64 B/row, upper-triangle blocks (symmetry). EXACT R10 kernel
// (last known good: 119 µs, passed, profiled) — dbuf LDS, rolled K-loop,
// 2-way swizzle, one b128 per fragment, packed-key DPP epilogue.
// The no-LDS rewrite (R11/R12) is shelved: container failed twice.
// ---------------------------------------------------------------------
__global__ __launch_bounds__(256, 3) void argmax_kernel(
    const unsigned char* __restrict__ xq,
    unsigned long long* __restrict__ best) {
    __shared__ unsigned char As[2][128 * 64];
    __shared__ unsigned char Bs[2][128 * 64];

    // decode upper-triangle pair: k -> (rb <= cb)
    int k = blockIdx.x;
    int i = (int)((sqrtf(8.0f * (float)k + 1.0f) - 1.0f) * 0.5f);
    while ((i + 1) * (i + 2) / 2 <= k) ++i;
    while (i * (i + 1) / 2 > k) --i;
    int cb = i;
    int rb = k - i * (i + 1) / 2;   // rb <= cb
    int r0 = rb * 128, c0 = cb * 128;

    int tid  = threadIdx.x;
    int wave = tid >> 6, lane = tid & 63;
    int wr = wave >> 1, wc = wave & 1;
    int quad = lane >> 4, l15 = lane & 15;

    f32x4 acc[4][4] = {};
    const int SC = 0x7f7f7f7f;      // e8m0 scales = 1.0 in every byte

    // staging pointers: 2 rounds x 256 threads cover 512 granules/tile
    const unsigned char* gA[2];
    const unsigned char* gB[2];
    int lofs[2];
#pragma unroll
    for (int r2 = 0; r2 < 2; ++r2) {
        int idx = r2 * 256 + tid;          // 0..511
        int r   = idx >> 2;                // 0..127
        int s   = idx & 3;                 // dst slot
        int g   = s ^ ((r ^ (r >> 2)) & 3);   // swizzled source granule
        gA[r2] = xq + (size_t)(r0 + r) * ROWB + (g << 4);
        gB[r2] = xq + (size_t)(c0 + r) * ROWB + (g << 4);
        lofs[r2] = idx * 16;
    }

    // fragment LDS offset: lane's 32 k-elems = source granule `quad`
    int s0 = ((quad ^ ((l15 ^ (l15 >> 2)) & 3)) << 4);

    auto stage = [&](int k0b, int buf) {
        async_copy16(gA[0] + k0b, &As[buf][lofs[0]]);
        async_copy16(gA[1] + k0b, &As[buf][lofs[1]]);
        async_copy16(gB[0] + k0b, &Bs[buf][lofs[0]]);
        async_copy16(gB[1] + k0b, &Bs[buf][lofs[1]]);
    };
    auto compute = [&](int buf) {
        const unsigned char* Ab = As[buf];
        const unsigned char* Bb = Bs[buf];
        int8v bfr[4];
#pragma unroll
        for (int t = 0; t < 4; ++t)
            bfr[t] = to8(*(const int4v*)(&Bb[(wc * 64 + t * 16 + l15) * 64 + s0]));
#pragma unroll
        for (int ti = 0; ti < 4; ++ti) {
            int8v a8 = to8(*(const int4v*)(&Ab[(wr * 64 + ti * 16 + l15) * 64 + s0]));
#pragma unroll
            for (int tj = 0; tj < 4; ++tj)
                acc[ti][tj] = __builtin_amdgcn_mfma_scale_f32_16x16x128_f8f6f4(
                    a8, bfr[tj], acc[ti][tj], 4, 4, 0, SC, 0, SC);
        }
    };

    stage(0, 0);
    __syncthreads();
    int buf = 0;
#pragma unroll 1
    for (int k0b = 64; k0b < ROWB; k0b += 64) {   // 5 pipelined steps
        stage(k0b, buf ^ 1);
        compute(buf);
        __syncthreads();
        buf ^= 1;
    }
    compute(buf);                // last tile; epilogue is register-only

    int rbase = r0 + wr * 64, cbase = c0 + wc * 64;

    // Row-direction: packed key = mono(v)&~63 | (tj<<4) | l15; DPP reduce.
#pragma unroll
    for (int ti = 0; ti < 4; ++ti) {
#pragma unroll
        for (int reg = 0; reg < 4; ++reg) {
            int grow = rbase + ti * 16 + quad * 4 + reg;
            unsigned bk = 0;
#pragma unroll
            for (int tj = 0; tj < 4; ++tj) {
                float v   = acc[ti][tj][reg];
                int  gcol = cbase + tj * 16 + l15;
                if (gcol == grow) v = -1.0e30f;   // diagonal mask
                unsigned u = (mono_u32(v) & ~63u) | (unsigned)((tj << 4) | l15);
                bk = bk > u ? bk : u;
            }
            bk = row_max_step<0x121>(bk);   // ror 1
            bk = row_max_step<0x122>(bk);   // ror 2
            bk = row_max_step<0x124>(bk);   // ror 4
            bk = row_max_step<0x128>(bk);   // ror 8
            if (l15 == 0) {
                int col = cbase + (int)(((bk >> 4) & 3u) * 16u + (bk & 15u));
                unsigned long long gk =
                    ((unsigned long long)(bk & ~63u) << 32) | (unsigned)col;
                atomicMax(&best[grow], gk);
            }
        }
    }

    // Column-direction (off-diagonal blocks)
    if (rb != cb) {
#pragma unroll
        for (int tj = 0; tj < 4; ++tj) {
            unsigned bk = 0;
#pragma unroll
            for (int ti = 0; ti < 4; ++ti)
#pragma unroll
                for (int reg = 0; reg < 4; ++reg) {
                    unsigned u = (mono_u32(acc[ti][tj][reg]) & ~63u) |
                                 (unsigned)((ti << 4) | (quad << 2) | reg);
                    bk = bk > u ? bk : u;
                }
            unsigned t16 = (unsigned)__shfl_xor((int)bk, 16, 64);
            bk = bk > t16 ? bk : t16;
            unsigned t32 = (unsigned)__shfl_xor((int)bk, 32, 64);
            bk = bk > t32 ? bk : t32;
            if (quad == 0) {
                int grow = rbase + (int)(((bk >> 4) & 3u) * 16u +
                                         ((bk >> 2) & 3u) * 4u + (bk & 3u));
                int gcol = cbase + tj * 16 + l15;
                unsigned long long gk =
                    ((unsigned long long)(bk & ~63u) << 32) | (unsigned)grow;
                atomicMax(&best[gcol], gk);
            }
        }
    }
}

// ---------------------------------------------------------------------
// Kernel 3a: fused loss+reduce from bf16 normalized rows. 256 blocks,
// 64 rows/block (16 per wave), per-block partial, one atomicAdd each.
// out[0] zeroed by normalize (stream-ordered).
// ---------------------------------------------------------------------
__global__ __launch_bounds__(256) void loss_bf16_kernel(
    const unsigned* __restrict__ xb,
    const unsigned long long* __restrict__ best,
    float* __restrict__ out) {
    __shared__ float part[4];
    int wave = threadIdx.x >> 6;
    int lane = threadIdx.x & 63;
    float accum = 0.0f;
#pragma unroll 1
    for (int it2 = 0; it2 < 16; ++it2) {
        int row = blockIdx.x * 64 + wave * 16 + it2;
        int j = (int)(best[row] & 0xffffffffull);
        const uint2* pi = (const uint2*)(xb + (size_t)row * (DFULL / 2));
        const uint2* pj = (const uint2*)(xb + (size_t)j   * (DFULL / 2));
        float s = 0.0f;
#pragma unroll
        for (int it = 0; it < 3; ++it) {
            int kk = lane + 64 * it;
            uint2 wi = pi[kk], wj = pj[kk];
            float d0 = bf_lo(wi.x) - bf_lo(wj.x) + EPSF;
            float d1 = bf_hi(wi.x) - bf_hi(wj.x) + EPSF;
            float d2 = bf_lo(wi.y) - bf_lo(wj.y) + EPSF;
            float d3 = bf_hi(wi.y) - bf_hi(wj.y) + EPSF;
            s += d0 * d0 + d1 * d1 + d2 * d2 + d3 * d3;
        }
#pragma unroll
        for (int d = 1; d < 64; d <<= 1) s += __shfl_xor(s, d, 64);
        if (lane == 0) accum += logf(sqrtf(s) + EPSF);
    }
    if (lane == 0) part[wave] = accum;
    __syncthreads();
    if (threadIdx.x == 0)
        atomicAdd(out, -(part[0] + part[1] + part[2] + part[3]) *
                       (1.0f / (float)NROWS));
}

// ---------------------------------------------------------------------
// Kernel 3b: fallback — fused loss+reduce from fp32 originals
// ---------------------------------------------------------------------
__global__ __launch_bounds__(256) void loss_kernel(
    const float* __restrict__ a, const float* __restrict__ b,
    const float* __restrict__ invn,
    const unsigned long long* __restrict__ best,
    float* __restrict__ out) {
    __shared__ float part[4];
    int wave = threadIdx.x >> 6;
    int lane = threadIdx.x & 63;
    float accum = 0.0f;
#pragma unroll 1
    for (int it2 = 0; it2 < 16; ++it2) {
        int row = blockIdx.x * 64 + wave * 16 + it2;
        int j = (int)(best[row] & 0xffffffffull);
        float ii = invn[row], ij = invn[j];
        const float2* pai = (const float2*)(a + (size_t)row * DHALF);
        const float2* pbi = (const float2*)(b + (size_t)row * DHALF);
        const float2* paj = (const float2*)(a + (size_t)j * DHALF);
        const float2* pbj = (const float2*)(b + (size_t)j * DHALF);
        float s = 0.0f;
#pragma unroll
        for (int it = 0; it < 3; ++it) {
            int kk = lane + 64 * it;
            float2 di = pai[kk], dj = paj[kk];
            float dx = di.x * ii - dj.x * ij + EPSF;
            float dy = di.y * ii - dj.y * ij + EPSF;
            s += dx * dx + dy * dy;
        }
#pragma unroll
        for (int it = 0; it < 3; ++it) {
            int kk = lane + 64 * it;
            float2 di = pbi[kk], dj = pbj[kk];
            float dx = di.x * ii - dj.x * ij + EPSF;
            float dy = di.y * ii - dj.y * ij + EPSF;
            s += dx * dx + dy * dy;
        }
#pragma unroll
        for (int d = 1; d < 64; d <<= 1) s += __shfl_xor(s, d, 64);
        if (lane == 0) accum += logf(sqrtf(s) + EPSF);
    }
    if (lane == 0) part[wave] = accum;
    __syncthreads();
    if (threadIdx.x == 0)
        atomicAdd(out, -(part[0] + part[1] + part[2] + part[3]) *
                       (1.0f / (float)NROWS));
}

// ---------------------------------------------------------------------
extern "C" void kernel_launch(void* const* d_in, const int* in_sizes, int n_in,
                              void* d_out, int out_size, void* d_ws, size_t ws_size,
                              hipStream_t stream) {
    const float* a = (const float*)d_in[0];
    const float* b = (const float*)d_in[1];
    float* out = (float*)d_out;

    char* ws = (char*)d_ws;
    unsigned char* xq = (unsigned char*)ws;                                    // 6291456 B
    unsigned long long* best = (unsigned long long*)(ws + 6291456);            // 131072 B
    float* invn  = (float*)(ws + 6291456 + 131072);                            // 65536 B
    unsigned* xb = (unsigned*)(ws + 6291456 + 131072 + 65536);                 // 25165824 B
    const size_t need_xb = 6291456ull + 131072 + 65536 + 25165824;
    const bool use_xb = ws_size >= need_xb;   // constant across calls

    const int NTILE = NROWS / 128;                     // 128
    const int NBLK  = NTILE * (NTILE + 1) / 2;         // 8256

    normalize_kernel<<<NROWS / 4, 256, 0, stream>>>(
        a, b, xq, invn, best, use_xb ? xb : (unsigned*)nullptr, out);
    argmax_kernel<<<NBLK, 256, 0, stream>>>(xq, best);
    if (use_xb)
        loss_bf16_kernel<<<NROWS / 64, 256, 0, stream>>>(xb, best, out);
    else
        loss_kernel<<<NROWS / 64, 256, 0, stream>>>(a, b, invn, best, out);
}